// Round 16
// baseline (65.091 us; speedup 1.0000x reference)
//
#include <hip/hip_runtime.h>
#include <math.h>

typedef short bf16x8 __attribute__((ext_vector_type(8)));
typedef float f32x4 __attribute__((ext_vector_type(4)));

#define MFMA16(a, b, c) __builtin_amdgcn_mfma_f32_16x16x32_bf16((a), (b), (c), 0, 0, 0)

#define TWO_PI_F 6.28318530717958647692f

// ---------------- ws layout: FRAGMENT-ORDERED bf16 weights (R11 proven) ----------------
// frag = 512 ushort = 64 lanes x 16B; lane ln=(kg*16+cf): row-part cf, k-part kg*8+e.
// pfw : [c:8][half:2][n_t:8][kk:9] ; w1: [n16:16][kk:6] ; expw: [n16:8] ; wout: [kk:9]
#define PFW_OFF    0
#define PFW_ELEMS  (8 * 2 * 8 * 9 * 512)      // 589,824
#define W1_OFF     (PFW_OFF + PFW_ELEMS)
#define W1_ELEMS   (16 * 6 * 512)             // 49,152
#define EXPW_OFF   (W1_OFF + W1_ELEMS)
#define EXPW_ELEMS (8 * 512)                  // 4,096
#define WOUT_OFF   (EXPW_OFF + EXPW_ELEMS)
#define WOUT_ELEMS (9 * 512)                  // 4,608
#define TOTAL_ELEMS (WOUT_OFF + WOUT_ELEMS)   // 647,680 ushorts -> 1,295,360 bytes

#define TILE_B 64

__device__ __forceinline__ unsigned short f2bf(float x) {
    unsigned int u = __float_as_uint(x);
    unsigned int r = u + 0x7fffu + ((u >> 16) & 1u);   // RNE
    return (unsigned short)(r >> 16);
}

__device__ __forceinline__ float elu_f(float x) {
    return x > 0.0f ? x : (expf(x) - 1.0f);
}

// async global->LDS, 16B per lane, linear both sides (R8-proven pattern)
__device__ __forceinline__ void gload_lds16(const void* g, void* l) {
    __builtin_amdgcn_global_load_lds(
        (const __attribute__((address_space(1))) void*)g,
        (__attribute__((address_space(3))) void*)l, 16, 0, 0);
}

// ---------------- prep: weight conversion to fragment order (R11 verbatim) ----------------
__global__ __launch_bounds__(256) void prep_weights(
    const float* __restrict__ exp_w, const float* __restrict__ w1,
    const float* __restrict__ pf_w, const float* __restrict__ w_out,
    unsigned short* __restrict__ wsb)
{
    int i = blockIdx.x * blockDim.x + threadIdx.x;
    if (i >= TOTAL_ELEMS) return;
    float v;
    if (i < W1_OFF) {
        int f = i >> 9, e512 = i & 511;
        int ln = e512 >> 3, e = e512 & 7;
        int kgp = ln >> 4, cf = ln & 15;
        int kk = f % 9; int rest = f / 9;
        int n_t = rest & 7; int rest2 = rest >> 3;
        int half = rest2 & 1; int c = rest2 >> 1;
        int n = half * 128 + n_t * 16 + cf;
        int k = kk * 32 + kgp * 8 + e;
        v = pf_w[((size_t)(c * 256 + n)) * 288 + k];
    } else if (i < EXPW_OFF) {
        int j = i - W1_OFF;
        int f = j >> 9, e512 = j & 511;
        int ln = e512 >> 3, e = e512 & 7;
        int kgp = ln >> 4, cf = ln & 15;
        int kk = f % 6; int n16 = f / 6;
        int n = n16 * 16 + cf;
        int k = kk * 32 + kgp * 8 + e;
        v = (k < 168) ? w1[n * 168 + k] : 0.0f;
    } else if (i < WOUT_OFF) {
        int j = i - EXPW_OFF;
        int n16 = j >> 9; int e512 = j & 511;
        int ln = e512 >> 3, e = e512 & 7;
        int kgp = ln >> 4, cf = ln & 15;
        v = exp_w[(n16 * 16 + cf) * 32 + kgp * 8 + e];
    } else {
        int j = i - WOUT_OFF;
        int kk = j >> 9; int e512 = j & 511;
        int ln = e512 >> 3, e = e512 & 7;
        int kgp = ln >> 4, cf = ln & 15;
        int k = kk * 32 + kgp * 8 + e;
        v = w_out[cf * 288 + k];
    }
    wsb[i] = f2bf(v);
}

// ---------------- K_A: input + stage A + stage B, export X2 frags + blend weights ----------------
__global__ __launch_bounds__(512, 2) void k_a(
    const float* __restrict__ inputs,
    const float* __restrict__ exp_b,
    const float* __restrict__ cp,
    const float* __restrict__ b1,
    const unsigned short* __restrict__ wsb,
    unsigned short* __restrict__ x2b,      // [rt][36][512]
    float* __restrict__ wcT,               // [rt][8][64]
    int B)
{
    __shared__ __align__(16) unsigned short buf1[TILE_B * 296];
    __shared__ __align__(16) unsigned short buf2[TILE_B * 296];
    __shared__ float sWcT[8][TILE_B];

    const unsigned short* w1b   = wsb + W1_OFF;
    const unsigned short* expwb = wsb + EXPW_OFF;

    const int t    = threadIdx.x;
    const int w    = t >> 6;
    const int lane = t & 63;
    const int cfr  = lane & 15;
    const int kg   = lane >> 4;
    const int b0   = blockIdx.x * TILE_B;

    for (int i = t; i < TILE_B * 32; i += 512) {
        int row = i >> 5, j = i & 31;
        int grow = b0 + row;
        float v = (grow < B) ? inputs[(size_t)grow * 33 + 1 + j] : 0.0f;
        unsigned short bv = f2bf(v);
        buf1[row * 296 + 136 + j] = bv;   // X1 state
        buf2[row * 296 + 256 + j] = bv;   // X2 state
        buf1[row * 296 + 168 + j] = 0;    // X1 zero pad 168..199
    }
    if (t < TILE_B) {
        int grow = b0 + t;
        #pragma unroll
        for (int c = 0; c < 8; ++c) sWcT[c][t] = 0.0f;
        if (grow < B) {
            float ph = inputs[(size_t)grow * 33];
            float p = fmodf(ph, TWO_PI_F);
            if (p < 0.0f) p += TWO_PI_F;
            float pos = p * (8.0f / TWO_PI_F);
            int base = (int)floorf(pos);
            float tt = pos - (float)base;
            base &= 7;
            float t2 = tt * tt, t3 = t2 * tt;
            float cw0 = -0.5f * tt + t2 - 0.5f * t3;
            float cw1 = 1.0f - 2.5f * t2 + 1.5f * t3;
            float cw2 = 0.5f * tt + 2.0f * t2 - 1.5f * t3;
            float cw3 = -0.5f * t2 + 0.5f * t3;
            int i0 = (base + 7) & 7, i1 = base, i2 = (base + 1) & 7, i3 = (base + 2) & 7;
            sWcT[i0][t] += cw0;
            sWcT[i1][t] += cw1;
            sWcT[i2][t] += cw2;
            sWcT[i3][t] += cw3;
            #pragma unroll
            for (int j = 0; j < 8; ++j) {
                float pn = cw0 * cp[i0 * 8 + j] + cw1 * cp[i1 * 8 + j]
                         + cw2 * cp[i2 * 8 + j] + cw3 * cp[i3 * 8 + j];
                buf1[t * 296 + 128 + j] = f2bf(pn);
            }
        } else {
            #pragma unroll
            for (int j = 0; j < 8; ++j) buf1[t * 296 + 128 + j] = 0;
        }
        #pragma unroll
        for (int c = 0; c < 8; ++c)
            wcT[(size_t)blockIdx.x * 512 + c * 64 + t] = sWcT[c][t];
    }
    __syncthreads();

    // ---- stage A: expanded = elu(state @ exp_w.T + exp_b)   N=128, K=32 ----
    {
        const int n0 = w * 16;
        bf16x8 bw = *(const bf16x8*)(expwb + w * 512 + lane * 8);
        const f32x4 zero = {0.f, 0.f, 0.f, 0.f};
        f32x4 acc[4];
        #pragma unroll
        for (int m = 0; m < 4; ++m) {
            bf16x8 a = *(const bf16x8*)&buf1[(m * 16 + cfr) * 296 + 136 + kg * 8];
            acc[m] = MFMA16(a, bw, zero);
        }
        float bias = exp_b[n0 + cfr];
        #pragma unroll
        for (int m = 0; m < 4; ++m)
            #pragma unroll
            for (int r = 0; r < 4; ++r) {
                int row = m * 16 + kg * 4 + r;
                buf1[row * 296 + n0 + cfr] = f2bf(elu_f(acc[m][r] + bias));
            }
    }
    __syncthreads();

    // ---- stage B: h1 = elu(X1 @ w1.T + b1)   N=256, K=192 (padded) ----
    {
        const int n0 = w * 32;
        f32x4 acc[2][4];
        #pragma unroll
        for (int nt = 0; nt < 2; ++nt)
            #pragma unroll
            for (int m = 0; m < 4; ++m)
                acc[nt][m] = (f32x4){0.f, 0.f, 0.f, 0.f};
        #pragma unroll
        for (int kk = 0; kk < 6; ++kk) {
            bf16x8 a[4];
            #pragma unroll
            for (int m = 0; m < 4; ++m)
                a[m] = *(const bf16x8*)&buf1[(m * 16 + cfr) * 296 + kk * 32 + kg * 8];
            #pragma unroll
            for (int nt = 0; nt < 2; ++nt) {
                bf16x8 bw = *(const bf16x8*)(w1b + ((w * 2 + nt) * 6 + kk) * 512 + lane * 8);
                #pragma unroll
                for (int m = 0; m < 4; ++m)
                    acc[nt][m] = MFMA16(a[m], bw, acc[nt][m]);
            }
        }
        #pragma unroll
        for (int nt = 0; nt < 2; ++nt) {
            float bias = b1[n0 + nt * 16 + cfr];
            #pragma unroll
            for (int m = 0; m < 4; ++m)
                #pragma unroll
                for (int r = 0; r < 4; ++r) {
                    int row = m * 16 + kg * 4 + r;
                    buf2[row * 296 + n0 + nt * 16 + cfr] = f2bf(elu_f(acc[nt][m][r] + bias));
                }
        }
    }
    __syncthreads();

    // ---- export X2 as 36 fragment-ordered coalesced 1KB stores ----
    for (int f = w; f < 36; f += 8) {
        int m = f / 9, kk = f - m * 9;
        bf16x8 v = *(const bf16x8*)&buf2[(m * 16 + cfr) * 296 + kk * 32 + kg * 8];
        *(bf16x8*)(x2b + (size_t)blockIdx.x * 18432 + f * 512 + lane * 8) = v;
    }
}

// ---------------- K_C: stage C only, col-quartered, lean registers ----------------
// grid = ntiles*4; block = 256 thr (4 waves). LDS 38.9KB -> 4 blocks/CU if regs<=128.
__global__ __launch_bounds__(256, 2) void k_c(
    const unsigned short* __restrict__ wsb,
    const unsigned short* __restrict__ x2b,
    const float* __restrict__ wcT,
    const float* __restrict__ pf_b,
    unsigned short* __restrict__ xoutb)    // [rt][32][512] (h2 frags)
{
    __shared__ __align__(16) unsigned short sX2[36 * 512];
    __shared__ __align__(16) float sWc[8][64];

    const unsigned short* pfwb = wsb + PFW_OFF;
    const int t    = threadIdx.x;
    const int w    = t >> 6;
    const int lane = t & 63;
    const int cfr  = lane & 15;
    const int kg   = lane >> 4;
    const int rt   = blockIdx.x >> 2;
    const int q    = blockIdx.x & 3;

    // DMA X2 tile (36,864B) + blend weights (2,048B) into LDS
    {
        const char* src = (const char*)(x2b + (size_t)rt * 18432);
        char* dst = (char*)sX2;
        #pragma unroll
        for (int it = 0; it < 9; ++it)
            gload_lds16(src + (it * 256 + t) * 16, dst + (it * 256 + t) * 16);
        if (t < 128)
            gload_lds16((const char*)(wcT + (size_t)rt * 512) + t * 16,
                        (char*)sWc + t * 16);
    }
    __syncthreads();

    const int g = q * 4 + w;               // 16-col group 0..15
    const size_t fb = (size_t)(((g >> 3) * 8 + (g & 7)) * 9) * 512 + lane * 8;
    const int col = q * 64 + w * 16 + cfr;

    f32x4 h2acc[4];
    #pragma unroll
    for (int m = 0; m < 4; ++m) h2acc[m] = (f32x4){0.f, 0.f, 0.f, 0.f};

    for (int c = 0; c < 8; ++c) {
        const unsigned short* wp = pfwb + (size_t)(c * 2 * 8 * 9) * 512 + fb;
        f32x4 z[4];
        #pragma unroll
        for (int m = 0; m < 4; ++m) z[m] = (f32x4){0.f, 0.f, 0.f, 0.f};
        #pragma unroll
        for (int kk = 0; kk < 9; ++kk) {
            bf16x8 bw = *(const bf16x8*)(wp + kk * 512);
            #pragma unroll
            for (int m = 0; m < 4; ++m) {
                bf16x8 a = *(const bf16x8*)&sX2[(m * 9 + kk) * 512 + lane * 8];
                z[m] = MFMA16(a, bw, z[m]);
            }
        }
        float pfb = pf_b[c * 256 + col];
        #pragma unroll
        for (int m = 0; m < 4; ++m) {
            f32x4 wcv = *(const f32x4*)&sWc[c][m * 16 + kg * 4];
            #pragma unroll
            for (int r = 0; r < 4; ++r)
                h2acc[m][r] += wcv[r] * (z[m][r] + pfb);
        }
    }

    // write h2 into fragment-ordered xoutb (16B-granule scattered stores)
    const int kkG = q * 2 + (w >> 1);
    const int lif = ((w & 1) * 2 + (cfr >> 3)) * 16;
    unsigned short* ob = xoutb + (size_t)rt * 16384;
    #pragma unroll
    for (int m = 0; m < 4; ++m)
        #pragma unroll
        for (int r = 0; r < 4; ++r)
            ob[(m * 8 + kkG) * 512 + (lif + kg * 4 + r) * 8 + (cfr & 7)]
                = f2bf(elu_f(h2acc[m][r]));
}

// ---------------- K_D: stage D from fragment-order h2 + state ----------------
__global__ __launch_bounds__(256, 2) void k_d(
    const unsigned short* __restrict__ wsb,
    const unsigned short* __restrict__ xoutb,
    const unsigned short* __restrict__ x2b,
    const float* __restrict__ b_out,
    float* __restrict__ out, int B)
{
    const unsigned short* woutb = wsb + WOUT_OFF;
    const int t    = threadIdx.x;
    const int w    = t >> 6;
    const int lane = t & 63;
    const int cfr  = lane & 15;
    const int kg   = lane >> 4;
    const int rt   = blockIdx.x;

    f32x4 acc = {0.f, 0.f, 0.f, 0.f};
    #pragma unroll
    for (int kk = 0; kk < 8; ++kk) {
        bf16x8 a  = *(const bf16x8*)(xoutb + (size_t)rt * 16384 + (w * 8 + kk) * 512 + lane * 8);
        bf16x8 bw = *(const bf16x8*)(woutb + kk * 512 + lane * 8);
        acc = MFMA16(a, bw, acc);
    }
    {   // kk=8: state columns (from X2 frags)
        bf16x8 a  = *(const bf16x8*)(x2b + (size_t)rt * 18432 + (w * 9 + 8) * 512 + lane * 8);
        bf16x8 bw = *(const bf16x8*)(woutb + 8 * 512 + lane * 8);
        acc = MFMA16(a, bw, acc);
    }
    float bias = b_out[cfr];
    #pragma unroll
    for (int r = 0; r < 4; ++r) {
        int grow = rt * 64 + w * 16 + kg * 4 + r;
        if (grow < B) out[(size_t)grow * 16 + cfr] = acc[r] + bias;
    }
}

// ---------------- monolithic fallback: R11 exact (38.8 us proven) ----------------
__global__ __launch_bounds__(512, 2) void pfnn_mono(
    const float* __restrict__ inputs,
    const float* __restrict__ exp_b,
    const float* __restrict__ cp,
    const float* __restrict__ b1,
    const float* __restrict__ pf_b,
    const float* __restrict__ b_out,
    const unsigned short* __restrict__ wsb,
    float* __restrict__ out, int B)
{
    __shared__ __align__(16) unsigned short buf1[TILE_B * 296];
    __shared__ __align__(16) unsigned short buf2[TILE_B * 296];
    __shared__ float sWcT[8][TILE_B];

    const unsigned short* pfwb  = wsb + PFW_OFF;
    const unsigned short* w1b   = wsb + W1_OFF;
    const unsigned short* expwb = wsb + EXPW_OFF;
    const unsigned short* woutb = wsb + WOUT_OFF;

    const int t    = threadIdx.x;
    const int w    = t >> 6;
    const int lane = t & 63;
    const int cfr  = lane & 15;
    const int kg   = lane >> 4;
    const int b0   = blockIdx.x * TILE_B;

    for (int i = t; i < TILE_B * 32; i += 512) {
        int row = i >> 5, j = i & 31;
        int grow = b0 + row;
        float v = (grow < B) ? inputs[(size_t)grow * 33 + 1 + j] : 0.0f;
        unsigned short bv = f2bf(v);
        buf1[row * 296 + 136 + j] = bv;
        buf1[row * 296 + 256 + j] = bv;
        buf2[row * 296 + 256 + j] = bv;
        buf1[row * 296 + 168 + j] = 0;
    }
    if (t < TILE_B) {
        int grow = b0 + t;
        float ph = (grow < B) ? inputs[(size_t)grow * 33] : 0.0f;
        float p = fmodf(ph, TWO_PI_F);
        if (p < 0.0f) p += TWO_PI_F;
        float pos = p * (8.0f / TWO_PI_F);
        int base = (int)floorf(pos);
        float tt = pos - (float)base;
        base &= 7;
        float t2 = tt * tt, t3 = t2 * tt;
        float cw0 = -0.5f * tt + t2 - 0.5f * t3;
        float cw1 = 1.0f - 2.5f * t2 + 1.5f * t3;
        float cw2 = 0.5f * tt + 2.0f * t2 - 1.5f * t3;
        float cw3 = -0.5f * t2 + 0.5f * t3;
        int i0 = (base + 7) & 7, i1 = base, i2 = (base + 1) & 7, i3 = (base + 2) & 7;
        #pragma unroll
        for (int c = 0; c < 8; ++c) sWcT[c][t] = 0.0f;
        sWcT[i0][t] += cw0;
        sWcT[i1][t] += cw1;
        sWcT[i2][t] += cw2;
        sWcT[i3][t] += cw3;
        #pragma unroll
        for (int j = 0; j < 8; ++j) {
            float pn = cw0 * cp[i0 * 8 + j] + cw1 * cp[i1 * 8 + j]
                     + cw2 * cp[i2 * 8 + j] + cw3 * cp[i3 * 8 + j];
            buf1[t * 296 + 128 + j] = f2bf(pn);
        }
    }
    __syncthreads();

    {
        const int n0 = w * 16;
        bf16x8 bw = *(const bf16x8*)(expwb + w * 512 + lane * 8);
        const f32x4 zero = {0.f, 0.f, 0.f, 0.f};
        f32x4 acc[4];
        #pragma unroll
        for (int m = 0; m < 4; ++m) {
            bf16x8 a = *(const bf16x8*)&buf1[(m * 16 + cfr) * 296 + 136 + kg * 8];
            acc[m] = MFMA16(a, bw, zero);
        }
        float bias = exp_b[n0 + cfr];
        #pragma unroll
        for (int m = 0; m < 4; ++m)
            #pragma unroll
            for (int r = 0; r < 4; ++r) {
                int row = m * 16 + kg * 4 + r;
                buf1[row * 296 + n0 + cfr] = f2bf(elu_f(acc[m][r] + bias));
            }
    }
    __syncthreads();

    {
        const int n0 = w * 32;
        f32x4 acc[2][4];
        #pragma unroll
        for (int nt = 0; nt < 2; ++nt)
            #pragma unroll
            for (int m = 0; m < 4; ++m)
                acc[nt][m] = (f32x4){0.f, 0.f, 0.f, 0.f};
        #pragma unroll
        for (int kk = 0; kk < 6; ++kk) {
            bf16x8 a[4];
            #pragma unroll
            for (int m = 0; m < 4; ++m)
                a[m] = *(const bf16x8*)&buf1[(m * 16 + cfr) * 296 + kk * 32 + kg * 8];
            #pragma unroll
            for (int nt = 0; nt < 2; ++nt) {
                bf16x8 bw = *(const bf16x8*)(w1b + ((w * 2 + nt) * 6 + kk) * 512 + lane * 8);
                #pragma unroll
                for (int m = 0; m < 4; ++m)
                    acc[nt][m] = MFMA16(a[m], bw, acc[nt][m]);
            }
        }
        #pragma unroll
        for (int nt = 0; nt < 2; ++nt) {
            float bias = b1[n0 + nt * 16 + cfr];
            #pragma unroll
            for (int m = 0; m < 4; ++m)
                #pragma unroll
                for (int r = 0; r < 4; ++r) {
                    int row = m * 16 + kg * 4 + r;
                    buf2[row * 296 + n0 + nt * 16 + cfr] = f2bf(elu_f(acc[nt][m][r] + bias));
                }
        }
    }
    __syncthreads();

    {
        const int n0 = w * 32;
        const int g0 = w * 2;
        const size_t fb0 = (size_t)(((g0 >> 3) * 8 + (g0 & 7)) * 9) * 512 + lane * 8;
        const size_t fb1 = (size_t)((((g0 + 1) >> 3) * 8 + ((g0 + 1) & 7)) * 9) * 512 + lane * 8;

        f32x4 h2acc[2][4];
        #pragma unroll
        for (int nt = 0; nt < 2; ++nt)
            #pragma unroll
            for (int m = 0; m < 4; ++m)
                h2acc[nt][m] = (f32x4){0.f, 0.f, 0.f, 0.f};

        for (int c = 0; c < 8; ++c) {
            const unsigned short* wp0 = pfwb + (size_t)(c * 2 * 8 * 9) * 512 + fb0;
            const unsigned short* wp1 = pfwb + (size_t)(c * 2 * 8 * 9) * 512 + fb1;

            f32x4 z[2][4];
            #pragma unroll
            for (int nt = 0; nt < 2; ++nt)
                #pragma unroll
                for (int m = 0; m < 4; ++m)
                    z[nt][m] = (f32x4){0.f, 0.f, 0.f, 0.f};

            #pragma unroll
            for (int kk = 0; kk < 9; ++kk) {
                bf16x8 bw0 = *(const bf16x8*)(wp0 + kk * 512);
                bf16x8 bw1 = *(const bf16x8*)(wp1 + kk * 512);
                #pragma unroll
                for (int m = 0; m < 4; ++m) {
                    bf16x8 a = *(const bf16x8*)&buf2[(m * 16 + cfr) * 296 + kk * 32 + kg * 8];
                    z[0][m] = MFMA16(a, bw0, z[0][m]);
                    z[1][m] = MFMA16(a, bw1, z[1][m]);
                }
            }

            float pfb0 = pf_b[c * 256 + n0 + cfr];
            float pfb1 = pf_b[c * 256 + n0 + 16 + cfr];
            #pragma unroll
            for (int m = 0; m < 4; ++m) {
                f32x4 wcv = *(const f32x4*)&sWcT[c][m * 16 + kg * 4];
                #pragma unroll
                for (int r = 0; r < 4; ++r) {
                    h2acc[0][m][r] += wcv[r] * (z[0][m][r] + pfb0);
                    h2acc[1][m][r] += wcv[r] * (z[1][m][r] + pfb1);
                }
            }
        }
        #pragma unroll
        for (int nt = 0; nt < 2; ++nt)
            #pragma unroll
            for (int m = 0; m < 4; ++m)
                #pragma unroll
                for (int r = 0; r < 4; ++r) {
                    int row = m * 16 + kg * 4 + r;
                    buf1[row * 296 + n0 + nt * 16 + cfr] = f2bf(elu_f(h2acc[nt][m][r]));
                }
    }
    __syncthreads();

    if (w < 4) {
        f32x4 acc = {0.f, 0.f, 0.f, 0.f};
        #pragma unroll
        for (int kk = 0; kk < 9; ++kk) {
            bf16x8 a  = *(const bf16x8*)&buf1[(w * 16 + cfr) * 296 + kk * 32 + kg * 8];
            bf16x8 bw = *(const bf16x8*)(woutb + kk * 512 + lane * 8);
            acc = MFMA16(a, bw, acc);
        }
        float bias = b_out[cfr];
        #pragma unroll
        for (int r = 0; r < 4; ++r) {
            int grow = b0 + w * 16 + kg * 4 + r;
            if (grow < B) out[(size_t)grow * 16 + cfr] = acc[r] + bias;
        }
    }
}

// ---------------- fp32 fallback (round-1 kernel) ----------------
#define FB_TILE 16
#define FB_THREADS 256

__global__ __launch_bounds__(FB_THREADS) void pfnn_fused_f32(
    const float* __restrict__ inputs,
    const float* __restrict__ exp_w, const float* __restrict__ exp_b,
    const float* __restrict__ cp,
    const float* __restrict__ w1, const float* __restrict__ b1,
    const float* __restrict__ pf_w, const float* __restrict__ pf_b,
    const float* __restrict__ w_out, const float* __restrict__ b_out,
    float* __restrict__ out, int B)
{
    __shared__ float sState[FB_TILE][36];
    __shared__ float sFI[FB_TILE][172];
    __shared__ float sH2in[FB_TILE][292];
    __shared__ float sH2[FB_TILE][260];
    __shared__ float sWc[FB_TILE][8];
    __shared__ float sPhase[FB_TILE];

    const int t = threadIdx.x;
    const int b0 = blockIdx.x * FB_TILE;
    const int nb = min(FB_TILE, B - b0);

    for (int i = t; i < nb * 33; i += FB_THREADS) {
        int b = i / 33, j = i % 33;
        float v = inputs[(size_t)(b0 + b) * 33 + j];
        if (j == 0) sPhase[b] = v;
        else { sState[b][j-1] = v; sFI[b][136 + j-1] = v; sH2in[b][256 + j-1] = v; }
    }
    for (int i = nb * 33 + t; i < FB_TILE * 33; i += FB_THREADS) {
        int b = i / 33, j = i % 33;
        if (j == 0) sPhase[b] = 0.0f;
        else { sState[b][j-1] = 0.0f; sFI[b][136 + j-1] = 0.0f; sH2in[b][256 + j-1] = 0.0f; }
    }
    __syncthreads();
    {
        const int o = t & 127;
        const int bh = t >> 7;
        const float4* wrow = reinterpret_cast<const float4*>(exp_w + o * 32);
        float4 wv[8];
        #pragma unroll
        for (int q = 0; q < 8; ++q) wv[q] = wrow[q];
        const float bias = exp_b[o];
        for (int bi = bh; bi < FB_TILE; bi += 2) {
            float acc = bias;
            #pragma unroll
            for (int q = 0; q < 8; ++q) {
                acc += wv[q].x * sState[bi][q*4+0] + wv[q].y * sState[bi][q*4+1]
                     + wv[q].z * sState[bi][q*4+2] + wv[q].w * sState[bi][q*4+3];
            }
            sFI[bi][o] = elu_f(acc);
        }
    }
    if (t < FB_TILE) {
        float p = fmodf(sPhase[t], TWO_PI_F);
        if (p < 0.0f) p += TWO_PI_F;
        float pos = p * (8.0f / TWO_PI_F);
        int base = (int)floorf(pos);
        float tt = pos - (float)base;
        base &= 7;
        float t2 = tt*tt, t3 = t2*tt;
        float cw0 = -0.5f*tt + t2 - 0.5f*t3;
        float cw1 = 1.0f - 2.5f*t2 + 1.5f*t3;
        float cw2 = 0.5f*tt + 2.0f*t2 - 1.5f*t3;
        float cw3 = -0.5f*t2 + 0.5f*t3;
        int i0 = (base+7)&7, i1 = base, i2 = (base+1)&7, i3 = (base+2)&7;
        #pragma unroll
        for (int c = 0; c < 8; ++c) sWc[t][c] = 0.0f;
        sWc[t][i0] += cw0; sWc[t][i1] += cw1; sWc[t][i2] += cw2; sWc[t][i3] += cw3;
        #pragma unroll
        for (int j = 0; j < 8; ++j)
            sFI[t][128 + j] = cw0*cp[i0*8+j] + cw1*cp[i1*8+j] + cw2*cp[i2*8+j] + cw3*cp[i3*8+j];
    }
    __syncthreads();
    {
        const int o = t;
        float acc[FB_TILE];
        const float bias = b1[o];
        #pragma unroll
        for (int b = 0; b < FB_TILE; ++b) acc[b] = bias;
        const float* wrow = w1 + o * 168;
        for (int k4 = 0; k4 < 42; ++k4) {
            float4 wv = *reinterpret_cast<const float4*>(wrow + k4 * 4);
            #pragma unroll
            for (int b = 0; b < FB_TILE; ++b) {
                float4 a = *reinterpret_cast<const float4*>(&sFI[b][k4 * 4]);
                acc[b] += wv.x*a.x + wv.y*a.y + wv.z*a.z + wv.w*a.w;
            }
        }
        #pragma unroll
        for (int b = 0; b < FB_TILE; ++b) sH2in[b][o] = elu_f(acc[b]);
    }
    __syncthreads();
    {
        const int o = t;
        float h2acc[FB_TILE];
        #pragma unroll
        for (int b = 0; b < FB_TILE; ++b) h2acc[b] = 0.0f;
        for (int g = 0; g < 2; ++g) {
            float zacc[FB_TILE][4];
            #pragma unroll
            for (int b = 0; b < FB_TILE; ++b)
                #pragma unroll
                for (int ci = 0; ci < 4; ++ci) zacc[b][ci] = 0.0f;
            for (int k4 = 0; k4 < 72; ++k4) {
                float wv[4][4];
                #pragma unroll
                for (int ci = 0; ci < 4; ++ci) {
                    float4 v = *reinterpret_cast<const float4*>(
                        pf_w + (size_t)((g*4+ci) * 256 + o) * 288 + k4 * 4);
                    wv[ci][0]=v.x; wv[ci][1]=v.y; wv[ci][2]=v.z; wv[ci][3]=v.w;
                }
                #pragma unroll
                for (int b = 0; b < FB_TILE; ++b) {
                    float4 a = *reinterpret_cast<const float4*>(&sH2in[b][k4 * 4]);
                    #pragma unroll
                    for (int ci = 0; ci < 4; ++ci)
                        zacc[b][ci] += a.x*wv[ci][0] + a.y*wv[ci][1] + a.z*wv[ci][2] + a.w*wv[ci][3];
                }
            }
            #pragma unroll
            for (int b = 0; b < FB_TILE; ++b)
                #pragma unroll
                for (int ci = 0; ci < 4; ++ci)
                    h2acc[b] += sWc[b][g*4+ci] * (zacc[b][ci] + pf_b[(g*4+ci) * 256 + o]);
        }
        #pragma unroll
        for (int b = 0; b < FB_TILE; ++b) sH2[b][o] = elu_f(h2acc[b]);
    }
    __syncthreads();
    {
        const int b = t >> 4;
        const int j = t & 15;
        const float* wrow = w_out + j * 288;
        float acc = b_out[j];
        for (int k4 = 0; k4 < 64; ++k4) {
            float4 wv = *reinterpret_cast<const float4*>(wrow + k4 * 4);
            float4 a = *reinterpret_cast<const float4*>(&sH2[b][k4 * 4]);
            acc += wv.x*a.x + wv.y*a.y + wv.z*a.z + wv.w*a.w;
        }
        #pragma unroll
        for (int j2 = 0; j2 < 32; ++j2) acc += wrow[256 + j2] * sState[b][j2];
        if (b < nb) out[(size_t)(b0 + b) * 16 + j] = acc;
    }
}

extern "C" void kernel_launch(void* const* d_in, const int* in_sizes, int n_in,
                              void* d_out, int out_size, void* d_ws, size_t ws_size,
                              hipStream_t stream) {
    const float* inputs = (const float*)d_in[0];
    const float* exp_w  = (const float*)d_in[1];
    const float* exp_b  = (const float*)d_in[2];
    const float* cp     = (const float*)d_in[3];
    const float* w1     = (const float*)d_in[4];
    const float* b1     = (const float*)d_in[5];
    const float* pf_w   = (const float*)d_in[6];
    const float* pf_b   = (const float*)d_in[7];
    const float* w_out  = (const float*)d_in[8];
    const float* b_out  = (const float*)d_in[9];
    float* out = (float*)d_out;

    const int B = in_sizes[0] / 33;
    const int ntl = (B + TILE_B - 1) / TILE_B;

    // ws: [wsb][x2b nt*36*512][xoutb nt*32*512] ushorts, then [wcT nt*512] floats
    const size_t wsb_e  = TOTAL_ELEMS;
    const size_t x2_e   = (size_t)ntl * 36 * 512;
    const size_t xo_e   = (size_t)ntl * 32 * 512;
    const size_t need_split = (wsb_e + x2_e + xo_e) * 2 + (size_t)ntl * 512 * 4;
    const size_t need_mono  = wsb_e * 2;

    if (d_ws != nullptr && ws_size >= need_split) {
        unsigned short* wsb   = (unsigned short*)d_ws;
        unsigned short* x2b   = wsb + wsb_e;
        unsigned short* xoutb = x2b + x2_e;
        float*          wcT   = (float*)(xoutb + xo_e);

        prep_weights<<<(TOTAL_ELEMS + 255) / 256, 256, 0, stream>>>(
            exp_w, w1, pf_w, w_out, wsb);
        k_a<<<ntl, 512, 0, stream>>>(inputs, exp_b, cp, b1, wsb, x2b, wcT, B);
        k_c<<<ntl * 4, 256, 0, stream>>>(wsb, x2b, wcT, pf_b, xoutb);
        k_d<<<ntl, 256, 0, stream>>>(wsb, xoutb, x2b, b_out, out, B);
    } else if (d_ws != nullptr && ws_size >= need_mono) {
        unsigned short* wsb = (unsigned short*)d_ws;
        prep_weights<<<(TOTAL_ELEMS + 255) / 256, 256, 0, stream>>>(
            exp_w, w1, pf_w, w_out, wsb);
        pfnn_mono<<<ntl, 512, 0, stream>>>(
            inputs, exp_b, cp, b1, pf_b, b_out, wsb, out, B);
    } else {
        pfnn_fused_f32<<<(B + FB_TILE - 1) / FB_TILE, FB_THREADS, 0, stream>>>(
            inputs, exp_w, exp_b, cp, w1, b1, pf_w, pf_b, w_out, b_out, out, B);
    }
}

// Round 17
// 40.949 us; speedup vs baseline: 1.5896x; 1.5896x over previous
//
#include <hip/hip_runtime.h>
#include <math.h>

typedef short bf16x8 __attribute__((ext_vector_type(8)));
typedef float f32x4 __attribute__((ext_vector_type(4)));

#define MFMA16(a, b, c) __builtin_amdgcn_mfma_f32_16x16x32_bf16((a), (b), (c), 0, 0, 0)

#define TWO_PI_F 6.28318530717958647692f

// ---------------- ws layout: FRAGMENT-ORDERED bf16 weights (R11 proven) ----------------
// frag = 512 ushort = 64 lanes x 16B; lane ln=(kg*16+cf): row-part cf, k-part kg*8+e.
// pfw : [c:8][half:2][n_t:8][kk:9] ; w1: [n16:16][kk:6] ; expw: [n16:8] ; wout: [kk:9]
#define PFW_OFF    0
#define PFW_ELEMS  (8 * 2 * 8 * 9 * 512)      // 589,824
#define W1_OFF     (PFW_OFF + PFW_ELEMS)
#define W1_ELEMS   (16 * 6 * 512)             // 49,152
#define EXPW_OFF   (W1_OFF + W1_ELEMS)
#define EXPW_ELEMS (8 * 512)                  // 4,096
#define WOUT_OFF   (EXPW_OFF + EXPW_ELEMS)
#define WOUT_ELEMS (9 * 512)                  // 4,608
#define TOTAL_ELEMS (WOUT_OFF + WOUT_ELEMS)   // 647,680 ushorts -> 1,295,360 bytes

#define MAIN_THREADS 512
#define TILE_B 64

__device__ __forceinline__ unsigned short f2bf(float x) {
    unsigned int u = __float_as_uint(x);
    unsigned int r = u + 0x7fffu + ((u >> 16) & 1u);   // RNE
    return (unsigned short)(r >> 16);
}

__device__ __forceinline__ float elu_f(float x) {
    return x > 0.0f ? x : (expf(x) - 1.0f);
}

// ---------------- prep: weight conversion to fragment order (R11 verbatim) ----------------
__global__ __launch_bounds__(256) void prep_weights(
    const float* __restrict__ exp_w, const float* __restrict__ w1,
    const float* __restrict__ pf_w, const float* __restrict__ w_out,
    unsigned short* __restrict__ wsb)
{
    int i = blockIdx.x * blockDim.x + threadIdx.x;
    if (i >= TOTAL_ELEMS) return;
    float v;
    if (i < W1_OFF) {
        int f = i >> 9, e512 = i & 511;
        int ln = e512 >> 3, e = e512 & 7;
        int kgp = ln >> 4, cf = ln & 15;
        int kk = f % 9; int rest = f / 9;
        int n_t = rest & 7; int rest2 = rest >> 3;
        int half = rest2 & 1; int c = rest2 >> 1;
        int n = half * 128 + n_t * 16 + cf;
        int k = kk * 32 + kgp * 8 + e;
        v = pf_w[((size_t)(c * 256 + n)) * 288 + k];
    } else if (i < EXPW_OFF) {
        int j = i - W1_OFF;
        int f = j >> 9, e512 = j & 511;
        int ln = e512 >> 3, e = e512 & 7;
        int kgp = ln >> 4, cf = ln & 15;
        int kk = f % 6; int n16 = f / 6;
        int n = n16 * 16 + cf;
        int k = kk * 32 + kgp * 8 + e;
        v = (k < 168) ? w1[n * 168 + k] : 0.0f;
    } else if (i < WOUT_OFF) {
        int j = i - EXPW_OFF;
        int n16 = j >> 9; int e512 = j & 511;
        int ln = e512 >> 3, e = e512 & 7;
        int kgp = ln >> 4, cf = ln & 15;
        v = exp_w[(n16 * 16 + cf) * 32 + kgp * 8 + e];
    } else {
        int j = i - WOUT_OFF;
        int kk = j >> 9; int e512 = j & 511;
        int ln = e512 >> 3, e = e512 & 7;
        int kgp = ln >> 4, cf = ln & 15;
        int k = kk * 32 + kgp * 8 + e;
        v = w_out[cf * 288 + k];
    }
    wsb[i] = f2bf(v);
}

// ---------------- main: R11 shell; stages B/C use batched b-load passes ----------------
__global__ __launch_bounds__(MAIN_THREADS, 2) void pfnn_mfma(
    const float* __restrict__ inputs,
    const float* __restrict__ exp_b,
    const float* __restrict__ cp,
    const float* __restrict__ b1,
    const float* __restrict__ pf_b,
    const float* __restrict__ b_out,
    const unsigned short* __restrict__ wsb,
    float* __restrict__ out, int B)
{
    // buf1: X1 = [expanded(0:128) | phase_nodes(128:136) | state(136:168) | 0(168:200)]
    //       later reused as Xout = [h2(0:256) | state(256:288)]
    // buf2: X2 = [h1(0:256) | state(256:288)]
    __shared__ __align__(16) unsigned short buf1[TILE_B * 296];
    __shared__ __align__(16) unsigned short buf2[TILE_B * 296];
    __shared__ float sWcT[8][TILE_B];

    const unsigned short* pfwb  = wsb + PFW_OFF;
    const unsigned short* w1b   = wsb + W1_OFF;
    const unsigned short* expwb = wsb + EXPW_OFF;
    const unsigned short* woutb = wsb + WOUT_OFF;

    const int t    = threadIdx.x;
    const int w    = t >> 6;        // wave 0..7
    const int lane = t & 63;
    const int cfr  = lane & 15;
    const int kg   = lane >> 4;
    const int b0   = blockIdx.x * TILE_B;

    // ---- staging: inputs -> LDS ----
    for (int i = t; i < TILE_B * 32; i += MAIN_THREADS) {
        int row = i >> 5, j = i & 31;
        int grow = b0 + row;
        float v = (grow < B) ? inputs[(size_t)grow * 33 + 1 + j] : 0.0f;
        unsigned short bv = f2bf(v);
        buf1[row * 296 + 136 + j] = bv;   // X1 state
        buf1[row * 296 + 256 + j] = bv;   // Xout state
        buf2[row * 296 + 256 + j] = bv;   // X2 state
        buf1[row * 296 + 168 + j] = 0;    // X1 zero pad 168..199
    }
    // ---- per-row Catmull-Rom phase weights + phase nodes ----
    if (t < TILE_B) {
        int grow = b0 + t;
        float ph = (grow < B) ? inputs[(size_t)grow * 33] : 0.0f;
        float p = fmodf(ph, TWO_PI_F);
        if (p < 0.0f) p += TWO_PI_F;
        float pos = p * (8.0f / TWO_PI_F);
        int base = (int)floorf(pos);
        float tt = pos - (float)base;
        base &= 7;
        float t2 = tt * tt, t3 = t2 * tt;
        float cw0 = -0.5f * tt + t2 - 0.5f * t3;
        float cw1 = 1.0f - 2.5f * t2 + 1.5f * t3;
        float cw2 = 0.5f * tt + 2.0f * t2 - 1.5f * t3;
        float cw3 = -0.5f * t2 + 0.5f * t3;
        int i0 = (base + 7) & 7, i1 = base, i2 = (base + 1) & 7, i3 = (base + 2) & 7;
        #pragma unroll
        for (int c = 0; c < 8; ++c) sWcT[c][t] = 0.0f;
        sWcT[i0][t] += cw0;
        sWcT[i1][t] += cw1;
        sWcT[i2][t] += cw2;
        sWcT[i3][t] += cw3;
        #pragma unroll
        for (int j = 0; j < 8; ++j) {
            float pn = cw0 * cp[i0 * 8 + j] + cw1 * cp[i1 * 8 + j]
                     + cw2 * cp[i2 * 8 + j] + cw3 * cp[i3 * 8 + j];
            buf1[t * 296 + 128 + j] = f2bf(pn);
        }
    }
    __syncthreads();

    // ---- stage A: expanded = elu(state @ exp_w.T + exp_b)   N=128, K=32 ----
    {
        const int n0 = w * 16;
        bf16x8 bw = *(const bf16x8*)(expwb + w * 512 + lane * 8);
        const f32x4 zero = {0.f, 0.f, 0.f, 0.f};
        f32x4 acc[4];
        #pragma unroll
        for (int m = 0; m < 4; ++m) {
            bf16x8 a = *(const bf16x8*)&buf1[(m * 16 + cfr) * 296 + 136 + kg * 8];
            acc[m] = MFMA16(a, bw, zero);
        }
        float bias = exp_b[n0 + cfr];
        #pragma unroll
        for (int m = 0; m < 4; ++m)
            #pragma unroll
            for (int r = 0; r < 4; ++r) {
                int row = m * 16 + kg * 4 + r;
                buf1[row * 296 + n0 + cfr] = f2bf(elu_f(acc[m][r] + bias));
            }
    }
    __syncthreads();

    // ---- stage B: h1 = elu(X1 @ w1.T + b1)   N=256, K=192 (padded) ----
    // per nt pass: preload all 6 b-frags -> one L2 round-trip, then MFMA chain
    {
        const int n0 = w * 32;
        #pragma unroll
        for (int nt = 0; nt < 2; ++nt) {
            bf16x8 bw[6];
            #pragma unroll
            for (int kk = 0; kk < 6; ++kk)
                bw[kk] = *(const bf16x8*)(w1b + ((w * 2 + nt) * 6 + kk) * 512 + lane * 8);
            f32x4 acc[4];
            #pragma unroll
            for (int m = 0; m < 4; ++m) acc[m] = (f32x4){0.f, 0.f, 0.f, 0.f};
            #pragma unroll
            for (int kk = 0; kk < 6; ++kk)
                #pragma unroll
                for (int m = 0; m < 4; ++m) {
                    bf16x8 a = *(const bf16x8*)&buf1[(m * 16 + cfr) * 296 + kk * 32 + kg * 8];
                    acc[m] = MFMA16(a, bw[kk], acc[m]);
                }
            float bias = b1[n0 + nt * 16 + cfr];
            #pragma unroll
            for (int m = 0; m < 4; ++m)
                #pragma unroll
                for (int r = 0; r < 4; ++r) {
                    int row = m * 16 + kg * 4 + r;
                    buf2[row * 296 + n0 + nt * 16 + cfr] = f2bf(elu_f(acc[m][r] + bias));
                }
        }
    }
    __syncthreads();

    // ---- stage C: 8-expert layer; per (nt,c) pass preloads bw[9] -> 1 round-trip ----
    {
        const int n0 = w * 32;
        #pragma unroll
        for (int nt = 0; nt < 2; ++nt) {
            const int g = w * 2 + nt;
            const size_t fb = (size_t)(((g >> 3) * 8 + (g & 7)) * 9) * 512 + lane * 8;

            f32x4 h2acc[4];
            #pragma unroll
            for (int m = 0; m < 4; ++m) h2acc[m] = (f32x4){0.f, 0.f, 0.f, 0.f};

            #pragma unroll 2
            for (int c = 0; c < 8; ++c) {
                const unsigned short* wp = pfwb + (size_t)(c * 144) * 512 + fb;
                bf16x8 bw[9];
                #pragma unroll
                for (int kk = 0; kk < 9; ++kk)
                    bw[kk] = *(const bf16x8*)(wp + kk * 512);

                f32x4 z[4];
                #pragma unroll
                for (int m = 0; m < 4; ++m) z[m] = (f32x4){0.f, 0.f, 0.f, 0.f};
                #pragma unroll
                for (int kk = 0; kk < 9; ++kk)
                    #pragma unroll
                    for (int m = 0; m < 4; ++m) {
                        bf16x8 a = *(const bf16x8*)&buf2[(m * 16 + cfr) * 296 + kk * 32 + kg * 8];
                        z[m] = MFMA16(a, bw[kk], z[m]);
                    }

                float pfb = pf_b[c * 256 + n0 + nt * 16 + cfr];
                #pragma unroll
                for (int m = 0; m < 4; ++m) {
                    f32x4 wcv = *(const f32x4*)&sWcT[c][m * 16 + kg * 4];
                    #pragma unroll
                    for (int r = 0; r < 4; ++r)
                        h2acc[m][r] += wcv[r] * (z[m][r] + pfb);
                }
            }
            // epilogue for this nt: h2 -> buf1 (X1 cols dead after stage B)
            #pragma unroll
            for (int m = 0; m < 4; ++m)
                #pragma unroll
                for (int r = 0; r < 4; ++r) {
                    int row = m * 16 + kg * 4 + r;
                    buf1[row * 296 + n0 + nt * 16 + cfr] = f2bf(elu_f(h2acc[m][r]));
                }
        }
    }
    __syncthreads();

    // ---- stage D: out = Xout @ w_out.T + b_out   N=16, K=288 ----
    if (w < 4) {
        f32x4 acc = {0.f, 0.f, 0.f, 0.f};
        #pragma unroll
        for (int kk = 0; kk < 9; ++kk) {
            bf16x8 a  = *(const bf16x8*)&buf1[(w * 16 + cfr) * 296 + kk * 32 + kg * 8];
            bf16x8 bw = *(const bf16x8*)(woutb + kk * 512 + lane * 8);
            acc = MFMA16(a, bw, acc);
        }
        float bias = b_out[cfr];
        #pragma unroll
        for (int r = 0; r < 4; ++r) {
            int grow = b0 + w * 16 + kg * 4 + r;
            if (grow < B) out[(size_t)grow * 16 + cfr] = acc[r] + bias;
        }
    }
}

// ---------------- fp32 fallback (round-1 kernel, direct pf_w reads) ----------------
#define FB_TILE 16
#define FB_THREADS 256

__global__ __launch_bounds__(FB_THREADS) void pfnn_fused_f32(
    const float* __restrict__ inputs,
    const float* __restrict__ exp_w, const float* __restrict__ exp_b,
    const float* __restrict__ cp,
    const float* __restrict__ w1, const float* __restrict__ b1,
    const float* __restrict__ pf_w, const float* __restrict__ pf_b,
    const float* __restrict__ w_out, const float* __restrict__ b_out,
    float* __restrict__ out, int B)
{
    __shared__ float sState[FB_TILE][36];
    __shared__ float sFI[FB_TILE][172];
    __shared__ float sH2in[FB_TILE][292];
    __shared__ float sH2[FB_TILE][260];
    __shared__ float sWc[FB_TILE][8];
    __shared__ float sPhase[FB_TILE];

    const int t = threadIdx.x;
    const int b0 = blockIdx.x * FB_TILE;
    const int nb = min(FB_TILE, B - b0);

    for (int i = t; i < nb * 33; i += FB_THREADS) {
        int b = i / 33, j = i % 33;
        float v = inputs[(size_t)(b0 + b) * 33 + j];
        if (j == 0) sPhase[b] = v;
        else { sState[b][j-1] = v; sFI[b][136 + j-1] = v; sH2in[b][256 + j-1] = v; }
    }
    for (int i = nb * 33 + t; i < FB_TILE * 33; i += FB_THREADS) {
        int b = i / 33, j = i % 33;
        if (j == 0) sPhase[b] = 0.0f;
        else { sState[b][j-1] = 0.0f; sFI[b][136 + j-1] = 0.0f; sH2in[b][256 + j-1] = 0.0f; }
    }
    __syncthreads();
    {
        const int o = t & 127;
        const int bh = t >> 7;
        const float4* wrow = reinterpret_cast<const float4*>(exp_w + o * 32);
        float4 wv[8];
        #pragma unroll
        for (int q = 0; q < 8; ++q) wv[q] = wrow[q];
        const float bias = exp_b[o];
        for (int bi = bh; bi < FB_TILE; bi += 2) {
            float acc = bias;
            #pragma unroll
            for (int q = 0; q < 8; ++q) {
                acc += wv[q].x * sState[bi][q*4+0] + wv[q].y * sState[bi][q*4+1]
                     + wv[q].z * sState[bi][q*4+2] + wv[q].w * sState[bi][q*4+3];
            }
            sFI[bi][o] = elu_f(acc);
        }
    }
    if (t < FB_TILE) {
        float p = fmodf(sPhase[t], TWO_PI_F);
        if (p < 0.0f) p += TWO_PI_F;
        float pos = p * (8.0f / TWO_PI_F);
        int base = (int)floorf(pos);
        float tt = pos - (float)base;
        base &= 7;
        float t2 = tt*tt, t3 = t2*tt;
        float cw0 = -0.5f*tt + t2 - 0.5f*t3;
        float cw1 = 1.0f - 2.5f*t2 + 1.5f*t3;
        float cw2 = 0.5f*tt + 2.0f*t2 - 1.5f*t3;
        float cw3 = -0.5f*t2 + 0.5f*t3;
        int i0 = (base+7)&7, i1 = base, i2 = (base+1)&7, i3 = (base+2)&7;
        #pragma unroll
        for (int c = 0; c < 8; ++c) sWc[t][c] = 0.0f;
        sWc[t][i0] += cw0; sWc[t][i1] += cw1; sWc[t][i2] += cw2; sWc[t][i3] += cw3;
        #pragma unroll
        for (int j = 0; j < 8; ++j)
            sFI[t][128 + j] = cw0*cp[i0*8+j] + cw1*cp[i1*8+j] + cw2*cp[i2*8+j] + cw3*cp[i3*8+j];
    }
    __syncthreads();
    {
        const int o = t;
        float acc[FB_TILE];
        const float bias = b1[o];
        #pragma unroll
        for (int b = 0; b < FB_TILE; ++b) acc[b] = bias;
        const float* wrow = w1 + o * 168;
        for (int k4 = 0; k4 < 42; ++k4) {
            float4 wv = *reinterpret_cast<const float4*>(wrow + k4 * 4);
            #pragma unroll
            for (int b = 0; b < FB_TILE; ++b) {
                float4 a = *reinterpret_cast<const float4*>(&sFI[b][k4 * 4]);
                acc[b] += wv.x*a.x + wv.y*a.y + wv.z*a.z + wv.w*a.w;
            }
        }
        #pragma unroll
        for (int b = 0; b < FB_TILE; ++b) sH2in[b][o] = elu_f(acc[b]);
    }
    __syncthreads();
    {
        const int o = t;
        float h2acc[FB_TILE];
        #pragma unroll
        for (int b = 0; b < FB_TILE; ++b) h2acc[b] = 0.0f;
        for (int g = 0; g < 2; ++g) {
            float zacc[FB_TILE][4];
            #pragma unroll
            for (int b = 0; b < FB_TILE; ++b)
                #pragma unroll
                for (int ci = 0; ci < 4; ++ci) zacc[b][ci] = 0.0f;
            for (int k4 = 0; k4 < 72; ++k4) {
                float wv[4][4];
                #pragma unroll
                for (int ci = 0; ci < 4; ++ci) {
                    float4 v = *reinterpret_cast<const float4*>(
                        pf_w + (size_t)((g*4+ci) * 256 + o) * 288 + k4 * 4);
                    wv[ci][0]=v.x; wv[ci][1]=v.y; wv[ci][2]=v.z; wv[ci][3]=v.w;
                }
                #pragma unroll
                for (int b = 0; b < FB_TILE; ++b) {
                    float4 a = *reinterpret_cast<const float4*>(&sH2in[b][k4 * 4]);
                    #pragma unroll
                    for (int ci = 0; ci < 4; ++ci)
                        zacc[b][ci] += a.x*wv[ci][0] + a.y*wv[ci][1] + a.z*wv[ci][2] + a.w*wv[ci][3];
                }
            }
            #pragma unroll
            for (int b = 0; b < FB_TILE; ++b)
                #pragma unroll
                for (int ci = 0; ci < 4; ++ci)
                    h2acc[b] += sWc[b][g*4+ci] * (zacc[b][ci] + pf_b[(g*4+ci) * 256 + o]);
        }
        #pragma unroll
        for (int b = 0; b < FB_TILE; ++b) sH2[b][o] = elu_f(h2acc[b]);
    }
    __syncthreads();
    {
        const int b = t >> 4;
        const int j = t & 15;
        const float* wrow = w_out + j * 288;
        float acc = b_out[j];
        for (int k4 = 0; k4 < 64; ++k4) {
            float4 wv = *reinterpret_cast<const float4*>(wrow + k4 * 4);
            float4 a = *reinterpret_cast<const float4*>(&sH2[b][k4 * 4]);
            acc += wv.x*a.x + wv.y*a.y + wv.z*a.z + wv.w*a.w;
        }
        #pragma unroll
        for (int j2 = 0; j2 < 32; ++j2) acc += wrow[256 + j2] * sState[b][j2];
        if (b < nb) out[(size_t)(b0 + b) * 16 + j] = acc;
    }
}

extern "C" void kernel_launch(void* const* d_in, const int* in_sizes, int n_in,
                              void* d_out, int out_size, void* d_ws, size_t ws_size,
                              hipStream_t stream) {
    const float* inputs = (const float*)d_in[0];
    const float* exp_w  = (const float*)d_in[1];
    const float* exp_b  = (const float*)d_in[2];
    const float* cp     = (const float*)d_in[3];
    const float* w1     = (const float*)d_in[4];
    const float* b1     = (const float*)d_in[5];
    const float* pf_w   = (const float*)d_in[6];
    const float* pf_b   = (const float*)d_in[7];
    const float* w_out  = (const float*)d_in[8];
    const float* b_out  = (const float*)d_in[9];
    float* out = (float*)d_out;

    const int B = in_sizes[0] / 33;
    const int ntl = (B + TILE_B - 1) / TILE_B;

    if (d_ws != nullptr && ws_size >= (size_t)TOTAL_ELEMS * sizeof(unsigned short)) {
        unsigned short* wsb = (unsigned short*)d_ws;
        prep_weights<<<(TOTAL_ELEMS + 255) / 256, 256, 0, stream>>>(
            exp_w, w1, pf_w, w_out, wsb);
        pfnn_mfma<<<ntl, MAIN_THREADS, 0, stream>>>(
            inputs, exp_b, cp, b1, pf_b, b_out, wsb, out, B);
    } else {
        pfnn_fused_f32<<<(B + FB_TILE - 1) / FB_TILE, FB_THREADS, 0, stream>>>(
            inputs, exp_w, exp_b, cp, w1, b1, pf_w, pf_b, w_out, b_out, out, B);
    }
}

// Round 18
// 38.747 us; speedup vs baseline: 1.6799x; 1.0568x over previous
//
#include <hip/hip_runtime.h>
#include <math.h>

typedef short bf16x8 __attribute__((ext_vector_type(8)));
typedef float f32x4 __attribute__((ext_vector_type(4)));

#define MFMA16(a, b, c) __builtin_amdgcn_mfma_f32_16x16x32_bf16((a), (b), (c), 0, 0, 0)

#define TWO_PI_F 6.28318530717958647692f

// ---------------- ws layout: FRAGMENT-ORDERED bf16 weights (R11 proven) ----------------
// frag = 512 ushort = 64 lanes x 16B; lane ln=(kg*16+cf): row-part cf, k-part kg*8+e.
// pfw : [c:8][half:2][n_t:8][kk:9] ; w1: [n16:16][kk:6] ; expw: [n16:8] ; wout: [kk:9]
#define PFW_OFF    0
#define PFW_ELEMS  (8 * 2 * 8 * 9 * 512)      // 589,824
#define W1_OFF     (PFW_OFF + PFW_ELEMS)
#define W1_ELEMS   (16 * 6 * 512)             // 49,152
#define EXPW_OFF   (W1_OFF + W1_ELEMS)
#define EXPW_ELEMS (8 * 512)                  // 4,096
#define WOUT_OFF   (EXPW_OFF + EXPW_ELEMS)
#define WOUT_ELEMS (9 * 512)                  // 4,608
#define TOTAL_ELEMS (WOUT_OFF + WOUT_ELEMS)   // 647,680 ushorts -> 1,295,360 bytes

#define MAIN_THREADS 512
#define TILE_B 64

__device__ __forceinline__ unsigned short f2bf(float x) {
    unsigned int u = __float_as_uint(x);
    unsigned int r = u + 0x7fffu + ((u >> 16) & 1u);   // RNE
    return (unsigned short)(r >> 16);
}

__device__ __forceinline__ float elu_f(float x) {
    return x > 0.0f ? x : (expf(x) - 1.0f);
}

// ---------------- prep: weight conversion to fragment order (R11 verbatim) ----------------
__global__ __launch_bounds__(256) void prep_weights(
    const float* __restrict__ exp_w, const float* __restrict__ w1,
    const float* __restrict__ pf_w, const float* __restrict__ w_out,
    unsigned short* __restrict__ wsb)
{
    int i = blockIdx.x * blockDim.x + threadIdx.x;
    if (i >= TOTAL_ELEMS) return;
    float v;
    if (i < W1_OFF) {
        int f = i >> 9, e512 = i & 511;
        int ln = e512 >> 3, e = e512 & 7;
        int kgp = ln >> 4, cf = ln & 15;
        int kk = f % 9; int rest = f / 9;
        int n_t = rest & 7; int rest2 = rest >> 3;
        int half = rest2 & 1; int c = rest2 >> 1;
        int n = half * 128 + n_t * 16 + cf;
        int k = kk * 32 + kgp * 8 + e;
        v = pf_w[((size_t)(c * 256 + n)) * 288 + k];
    } else if (i < EXPW_OFF) {
        int j = i - W1_OFF;
        int f = j >> 9, e512 = j & 511;
        int ln = e512 >> 3, e = e512 & 7;
        int kgp = ln >> 4, cf = ln & 15;
        int kk = f % 6; int n16 = f / 6;
        int n = n16 * 16 + cf;
        int k = kk * 32 + kgp * 8 + e;
        v = (k < 168) ? w1[n * 168 + k] : 0.0f;
    } else if (i < WOUT_OFF) {
        int j = i - EXPW_OFF;
        int n16 = j >> 9; int e512 = j & 511;
        int ln = e512 >> 3, e = e512 & 7;
        int kgp = ln >> 4, cf = ln & 15;
        v = exp_w[(n16 * 16 + cf) * 32 + kgp * 8 + e];
    } else {
        int j = i - WOUT_OFF;
        int kk = j >> 9; int e512 = j & 511;
        int ln = e512 >> 3, e = e512 & 7;
        int kgp = ln >> 4, cf = ln & 15;
        int k = kk * 32 + kgp * 8 + e;
        v = w_out[cf * 288 + k];
    }
    wsb[i] = f2bf(v);
}

// ---------------- main: R11 exact structure + s_setprio around stage-C MFMAs ----------------
__global__ __launch_bounds__(MAIN_THREADS, 2) void pfnn_mfma(
    const float* __restrict__ inputs,
    const float* __restrict__ exp_b,
    const float* __restrict__ cp,
    const float* __restrict__ b1,
    const float* __restrict__ pf_b,
    const float* __restrict__ b_out,
    const unsigned short* __restrict__ wsb,
    float* __restrict__ out, int B)
{
    // buf1: X1 = [expanded(0:128) | phase_nodes(128:136) | state(136:168) | 0(168:200)]
    //       later reused as Xout = [h2(0:256) | state(256:288)]
    // buf2: X2 = [h1(0:256) | state(256:288)]
    __shared__ __align__(16) unsigned short buf1[TILE_B * 296];
    __shared__ __align__(16) unsigned short buf2[TILE_B * 296];
    __shared__ float sWcT[8][TILE_B];

    const unsigned short* pfwb  = wsb + PFW_OFF;
    const unsigned short* w1b   = wsb + W1_OFF;
    const unsigned short* expwb = wsb + EXPW_OFF;
    const unsigned short* woutb = wsb + WOUT_OFF;

    const int t    = threadIdx.x;
    const int w    = t >> 6;        // wave 0..7
    const int lane = t & 63;
    const int cfr  = lane & 15;
    const int kg   = lane >> 4;
    const int b0   = blockIdx.x * TILE_B;

    // ---- staging: inputs -> LDS ----
    for (int i = t; i < TILE_B * 32; i += MAIN_THREADS) {
        int row = i >> 5, j = i & 31;
        int grow = b0 + row;
        float v = (grow < B) ? inputs[(size_t)grow * 33 + 1 + j] : 0.0f;
        unsigned short bv = f2bf(v);
        buf1[row * 296 + 136 + j] = bv;   // X1 state
        buf1[row * 296 + 256 + j] = bv;   // Xout state
        buf2[row * 296 + 256 + j] = bv;   // X2 state
        buf1[row * 296 + 168 + j] = 0;    // X1 zero pad 168..199
    }
    // ---- per-row Catmull-Rom phase weights + phase nodes ----
    if (t < TILE_B) {
        int grow = b0 + t;
        float ph = (grow < B) ? inputs[(size_t)grow * 33] : 0.0f;
        float p = fmodf(ph, TWO_PI_F);
        if (p < 0.0f) p += TWO_PI_F;
        float pos = p * (8.0f / TWO_PI_F);
        int base = (int)floorf(pos);
        float tt = pos - (float)base;
        base &= 7;
        float t2 = tt * tt, t3 = t2 * tt;
        float cw0 = -0.5f * tt + t2 - 0.5f * t3;
        float cw1 = 1.0f - 2.5f * t2 + 1.5f * t3;
        float cw2 = 0.5f * tt + 2.0f * t2 - 1.5f * t3;
        float cw3 = -0.5f * t2 + 0.5f * t3;
        int i0 = (base + 7) & 7, i1 = base, i2 = (base + 1) & 7, i3 = (base + 2) & 7;
        #pragma unroll
        for (int c = 0; c < 8; ++c) sWcT[c][t] = 0.0f;
        sWcT[i0][t] += cw0;
        sWcT[i1][t] += cw1;
        sWcT[i2][t] += cw2;
        sWcT[i3][t] += cw3;
        #pragma unroll
        for (int j = 0; j < 8; ++j) {
            float pn = cw0 * cp[i0 * 8 + j] + cw1 * cp[i1 * 8 + j]
                     + cw2 * cp[i2 * 8 + j] + cw3 * cp[i3 * 8 + j];
            buf1[t * 296 + 128 + j] = f2bf(pn);
        }
    }
    __syncthreads();

    // ---- stage A: expanded = elu(state @ exp_w.T + exp_b)   N=128, K=32 ----
    {
        const int n0 = w * 16;
        bf16x8 bw = *(const bf16x8*)(expwb + w * 512 + lane * 8);
        const f32x4 zero = {0.f, 0.f, 0.f, 0.f};
        f32x4 acc[4];
        #pragma unroll
        for (int m = 0; m < 4; ++m) {
            bf16x8 a = *(const bf16x8*)&buf1[(m * 16 + cfr) * 296 + 136 + kg * 8];
            acc[m] = MFMA16(a, bw, zero);
        }
        float bias = exp_b[n0 + cfr];
        #pragma unroll
        for (int m = 0; m < 4; ++m)
            #pragma unroll
            for (int r = 0; r < 4; ++r) {
                int row = m * 16 + kg * 4 + r;
                buf1[row * 296 + n0 + cfr] = f2bf(elu_f(acc[m][r] + bias));
            }
    }
    __syncthreads();

    // ---- stage B: h1 = elu(X1 @ w1.T + b1)   N=256, K=192 (padded) ----
    {
        const int n0 = w * 32;
        f32x4 acc[2][4];
        #pragma unroll
        for (int nt = 0; nt < 2; ++nt)
            #pragma unroll
            for (int m = 0; m < 4; ++m)
                acc[nt][m] = (f32x4){0.f, 0.f, 0.f, 0.f};
        #pragma unroll
        for (int kk = 0; kk < 6; ++kk) {
            bf16x8 a[4];
            #pragma unroll
            for (int m = 0; m < 4; ++m)
                a[m] = *(const bf16x8*)&buf1[(m * 16 + cfr) * 296 + kk * 32 + kg * 8];
            #pragma unroll
            for (int nt = 0; nt < 2; ++nt) {
                bf16x8 bw = *(const bf16x8*)(w1b + ((w * 2 + nt) * 6 + kk) * 512 + lane * 8);
                #pragma unroll
                for (int m = 0; m < 4; ++m)
                    acc[nt][m] = MFMA16(a[m], bw, acc[nt][m]);
            }
        }
        #pragma unroll
        for (int nt = 0; nt < 2; ++nt) {
            float bias = b1[n0 + nt * 16 + cfr];
            #pragma unroll
            for (int m = 0; m < 4; ++m)
                #pragma unroll
                for (int r = 0; r < 4; ++r) {
                    int row = m * 16 + kg * 4 + r;
                    buf2[row * 296 + n0 + nt * 16 + cfr] = f2bf(elu_f(acc[nt][m][r] + bias));
                }
        }
    }
    __syncthreads();

    // ---- stage C: dense 8-expert phase-function layer (R11 loop shape) ----
    // No internal barriers -> waves drift out of phase; setprio(1) around the MFMA
    // cluster lets MFMA-entering waves win the scheduler over load-issuing waves (T5).
    {
        const int n0 = w * 32;
        const int g0 = w * 2;
        const size_t fb0 = (size_t)(((g0 >> 3) * 8 + (g0 & 7)) * 9) * 512 + lane * 8;
        const size_t fb1 = (size_t)((((g0 + 1) >> 3) * 8 + ((g0 + 1) & 7)) * 9) * 512 + lane * 8;

        f32x4 h2acc[2][4];
        #pragma unroll
        for (int nt = 0; nt < 2; ++nt)
            #pragma unroll
            for (int m = 0; m < 4; ++m)
                h2acc[nt][m] = (f32x4){0.f, 0.f, 0.f, 0.f};

        for (int c = 0; c < 8; ++c) {
            const unsigned short* wp0 = pfwb + (size_t)(c * 2 * 8 * 9) * 512 + fb0;
            const unsigned short* wp1 = pfwb + (size_t)(c * 2 * 8 * 9) * 512 + fb1;

            f32x4 z[2][4];
            #pragma unroll
            for (int nt = 0; nt < 2; ++nt)
                #pragma unroll
                for (int m = 0; m < 4; ++m)
                    z[nt][m] = (f32x4){0.f, 0.f, 0.f, 0.f};

            __builtin_amdgcn_s_setprio(1);
            #pragma unroll
            for (int kk = 0; kk < 9; ++kk) {
                bf16x8 bw0 = *(const bf16x8*)(wp0 + kk * 512);
                bf16x8 bw1 = *(const bf16x8*)(wp1 + kk * 512);
                #pragma unroll
                for (int m = 0; m < 4; ++m) {
                    bf16x8 a = *(const bf16x8*)&buf2[(m * 16 + cfr) * 296 + kk * 32 + kg * 8];
                    z[0][m] = MFMA16(a, bw0, z[0][m]);
                    z[1][m] = MFMA16(a, bw1, z[1][m]);
                }
            }
            __builtin_amdgcn_s_setprio(0);

            float pfb0 = pf_b[c * 256 + n0 + cfr];
            float pfb1 = pf_b[c * 256 + n0 + 16 + cfr];
            #pragma unroll
            for (int m = 0; m < 4; ++m) {
                f32x4 wcv = *(const f32x4*)&sWcT[c][m * 16 + kg * 4];
                #pragma unroll
                for (int r = 0; r < 4; ++r) {
                    h2acc[0][m][r] += wcv[r] * (z[0][m][r] + pfb0);
                    h2acc[1][m][r] += wcv[r] * (z[1][m][r] + pfb1);
                }
            }
        }
        // epilogue: h2 -> buf1 cols 0..255 (state already at 256..287)
        #pragma unroll
        for (int nt = 0; nt < 2; ++nt)
            #pragma unroll
            for (int m = 0; m < 4; ++m)
                #pragma unroll
                for (int r = 0; r < 4; ++r) {
                    int row = m * 16 + kg * 4 + r;
                    buf1[row * 296 + n0 + nt * 16 + cfr] = f2bf(elu_f(h2acc[nt][m][r]));
                }
    }
    __syncthreads();

    // ---- stage D: out = Xout @ w_out.T + b_out   N=16, K=288 ----
    if (w < 4) {
        f32x4 acc = {0.f, 0.f, 0.f, 0.f};
        #pragma unroll
        for (int kk = 0; kk < 9; ++kk) {
            bf16x8 a  = *(const bf16x8*)&buf1[(w * 16 + cfr) * 296 + kk * 32 + kg * 8];
            bf16x8 bw = *(const bf16x8*)(woutb + kk * 512 + lane * 8);
            acc = MFMA16(a, bw, acc);
        }
        float bias = b_out[cfr];
        #pragma unroll
        for (int r = 0; r < 4; ++r) {
            int grow = b0 + w * 16 + kg * 4 + r;
            if (grow < B) out[(size_t)grow * 16 + cfr] = acc[r] + bias;
        }
    }
}

// ---------------- fp32 fallback (round-1 kernel, direct pf_w reads) ----------------
#define FB_TILE 16
#define FB_THREADS 256

__global__ __launch_bounds__(FB_THREADS) void pfnn_fused_f32(
    const float* __restrict__ inputs,
    const float* __restrict__ exp_w, const float* __restrict__ exp_b,
    const float* __restrict__ cp,
    const float* __restrict__ w1, const float* __restrict__ b1,
    const float* __restrict__ pf_w, const float* __restrict__ pf_b,
    const float* __restrict__ w_out, const float* __restrict__ b_out,
    float* __restrict__ out, int B)
{
    __shared__ float sState[FB_TILE][36];
    __shared__ float sFI[FB_TILE][172];
    __shared__ float sH2in[FB_TILE][292];
    __shared__ float sH2[FB_TILE][260];
    __shared__ float sWc[FB_TILE][8];
    __shared__ float sPhase[FB_TILE];

    const int t = threadIdx.x;
    const int b0 = blockIdx.x * FB_TILE;
    const int nb = min(FB_TILE, B - b0);

    for (int i = t; i < nb * 33; i += FB_THREADS) {
        int b = i / 33, j = i % 33;
        float v = inputs[(size_t)(b0 + b) * 33 + j];
        if (j == 0) sPhase[b] = v;
        else { sState[b][j-1] = v; sFI[b][136 + j-1] = v; sH2in[b][256 + j-1] = v; }
    }
    for (int i = nb * 33 + t; i < FB_TILE * 33; i += FB_THREADS) {
        int b = i / 33, j = i % 33;
        if (j == 0) sPhase[b] = 0.0f;
        else { sState[b][j-1] = 0.0f; sFI[b][136 + j-1] = 0.0f; sH2in[b][256 + j-1] = 0.0f; }
    }
    __syncthreads();
    {
        const int o = t & 127;
        const int bh = t >> 7;
        const float4* wrow = reinterpret_cast<const float4*>(exp_w + o * 32);
        float4 wv[8];
        #pragma unroll
        for (int q = 0; q < 8; ++q) wv[q] = wrow[q];
        const float bias = exp_b[o];
        for (int bi = bh; bi < FB_TILE; bi += 2) {
            float acc = bias;
            #pragma unroll
            for (int q = 0; q < 8; ++q) {
                acc += wv[q].x * sState[bi][q*4+0] + wv[q].y * sState[bi][q*4+1]
                     + wv[q].z * sState[bi][q*4+2] + wv[q].w * sState[bi][q*4+3];
            }
            sFI[bi][o] = elu_f(acc);
        }
    }
    if (t < FB_TILE) {
        float p = fmodf(sPhase[t], TWO_PI_F);
        if (p < 0.0f) p += TWO_PI_F;
        float pos = p * (8.0f / TWO_PI_F);
        int base = (int)floorf(pos);
        float tt = pos - (float)base;
        base &= 7;
        float t2 = tt*tt, t3 = t2*tt;
        float cw0 = -0.5f*tt + t2 - 0.5f*t3;
        float cw1 = 1.0f - 2.5f*t2 + 1.5f*t3;
        float cw2 = 0.5f*tt + 2.0f*t2 - 1.5f*t3;
        float cw3 = -0.5f*t2 + 0.5f*t3;
        int i0 = (base+7)&7, i1 = base, i2 = (base+1)&7, i3 = (base+2)&7;
        #pragma unroll
        for (int c = 0; c < 8; ++c) sWc[t][c] = 0.0f;
        sWc[t][i0] += cw0; sWc[t][i1] += cw1; sWc[t][i2] += cw2; sWc[t][i3] += cw3;
        #pragma unroll
        for (int j = 0; j < 8; ++j)
            sFI[t][128 + j] = cw0*cp[i0*8+j] + cw1*cp[i1*8+j] + cw2*cp[i2*8+j] + cw3*cp[i3*8+j];
    }
    __syncthreads();
    {
        const int o = t;
        float acc[FB_TILE];
        const float bias = b1[o];
        #pragma unroll
        for (int b = 0; b < FB_TILE; ++b) acc[b] = bias;
        const float* wrow = w1 + o * 168;
        for (int k4 = 0; k4 < 42; ++k4) {
            float4 wv = *reinterpret_cast<const float4*>(wrow + k4 * 4);
            #pragma unroll
            for (int b = 0; b < FB_TILE; ++b) {
                float4 a = *reinterpret_cast<const float4*>(&sFI[b][k4 * 4]);
                acc[b] += wv.x*a.x + wv.y*a.y + wv.z*a.z + wv.w*a.w;
            }
        }
        #pragma unroll
        for (int b = 0; b < FB_TILE; ++b) sH2in[b][o] = elu_f(acc[b]);
    }
    __syncthreads();
    {
        const int o = t;
        float h2acc[FB_TILE];
        #pragma unroll
        for (int b = 0; b < FB_TILE; ++b) h2acc[b] = 0.0f;
        for (int g = 0; g < 2; ++g) {
            float zacc[FB_TILE][4];
            #pragma unroll
            for (int b = 0; b < FB_TILE; ++b)
                #pragma unroll
                for (int ci = 0; ci < 4; ++ci) zacc[b][ci] = 0.0f;
            for (int k4 = 0; k4 < 72; ++k4) {
                float wv[4][4];
                #pragma unroll
                for (int ci = 0; ci < 4; ++ci) {
                    float4 v = *reinterpret_cast<const float4*>(
                        pf_w + (size_t)((g*4+ci) * 256 + o) * 288 + k4 * 4);
                    wv[ci][0]=v.x; wv[ci][1]=v.y; wv[ci][2]=v.z; wv[ci][3]=v.w;
                }
                #pragma unroll
                for (int b = 0; b < FB_TILE; ++b) {
                    float4 a = *reinterpret_cast<const float4*>(&sH2in[b][k4 * 4]);
                    #pragma unroll
                    for (int ci = 0; ci < 4; ++ci)
                        zacc[b][ci] += a.x*wv[ci][0] + a.y*wv[ci][1] + a.z*wv[ci][2] + a.w*wv[ci][3];
                }
            }
            #pragma unroll
            for (int b = 0; b < FB_TILE; ++b)
                #pragma unroll
                for (int ci = 0; ci < 4; ++ci)
                    h2acc[b] += sWc[b][g*4+ci] * (zacc[b][ci] + pf_b[(g*4+ci) * 256 + o]);
        }
        #pragma unroll
        for (int b = 0; b < FB_TILE; ++b) sH2[b][o] = elu_f(h2acc[b]);
    }
    __syncthreads();
    {
        const int b = t >> 4;
        const int j = t & 15;
        const float* wrow = w_out + j * 288;
        float acc = b_out[j];
        for (int k4 = 0; k4 < 64; ++k4) {
            float4 wv = *reinterpret_cast<const float4*>(wrow + k4 * 4);
            float4 a = *reinterpret_cast<const float4*>(&sH2[b][k4 * 4]);
            acc += wv.x*a.x + wv.y*a.y + wv.z*a.z + wv.w*a.w;
        }
        #pragma unroll
        for (int j2 = 0; j2 < 32; ++j2) acc += wrow[256 + j2] * sState[b][j2];
        if (b < nb) out[(size_t)(b0 + b) * 16 + j] = acc;
    }
}

extern "C" void kernel_launch(void* const* d_in, const int* in_sizes, int n_in,
                              void* d_out, int out_size, void* d_ws, size_t ws_size,
                              hipStream_t stream) {
    const float* inputs = (const float*)d_in[0];
    const float* exp_w  = (const float*)d_in[1];
    const float* exp_b  = (const float*)d_in[2];
    const float* cp     = (const float*)d_in[3];
    const float* w1     = (const float*)d_in[4];
    const float* b1     = (const float*)d_in[5];
    const float* pf_w   = (const float*)d_in[6];
    const float* pf_b   = (const float*)d_in[7];
    const float* w_out  = (const float*)d_in[8];
    const float* b_out  = (const float*)d_in[9];
    float* out = (float*)d_out;

    const int B = in_sizes[0] / 33;
    const int ntl = (B + TILE_B - 1) / TILE_B;

    if (d_ws != nullptr && ws_size >= (size_t)TOTAL_ELEMS * sizeof(unsigned short)) {
        unsigned short* wsb = (unsigned short*)d_ws;
        prep_weights<<<(TOTAL_ELEMS + 255) / 256, 256, 0, stream>>>(
            exp_w, w1, pf_w, w_out, wsb);
        pfnn_mfma<<<ntl, MAIN_THREADS, 0, stream>>>(
            inputs, exp_b, cp, b1, pf_b, b_out, wsb, out, B);
    } else {
        pfnn_fused_f32<<<(B + FB_TILE - 1) / FB_TILE, FB_THREADS, 0, stream>>>(
            inputs, exp_w, exp_b, cp, w1, b1, pf_w, pf_b, w_out, b_out, out, B);
    }
}